// Round 9
// baseline (49.393 us; speedup 1.0000x reference)
//
#include <hip/hip_runtime.h>
#include <cstdint>

// OnlineTripletLoss: emb (8192,512) f32, triplets (131072,3) int32.
// Proven: D-sharding (chunk=blockIdx%NCHUNK -> XCD) keeps sub-tables
// L2-resident (FETCH 310MB->14MB); fp16 table halves sectors; gather is
// throughput-walled at ~0.5 sector/cy/CU (MLP-insensitive, R4/R5/R8).
// R9: fuse p2+p3 via deterministic last-block ticket (saves 1 launch+gap).

#define MARGIN_INV (1.0f / 0.7f)
#define D 512
#define NCHUNK 4               // fp16 path: 4 chunks of 128 halfs (256 B)
#define CHUNKH 128

typedef _Float16 half2_t __attribute__((ext_vector_type(2)));
typedef _Float16 v8h     __attribute__((ext_vector_type(8)));

constexpr int P1_BLOCKS  = 4096;
constexpr int P1_THREADS = 256;        // 4 waves
constexpr int WPB        = P1_THREADS / 64;
constexpr int WAVES_PER_CHUNK = (P1_BLOCKS / NCHUNK) * WPB;   // 4096

// fp32 fallback path constants (proven R5 structure)
#define FNCHUNK 8
#define CHUNKF 64
constexpr int F_WPC = (P1_BLOCKS / FNCHUNK) * WPB;            // 2048

__device__ __forceinline__ float dot4(float4 a, float4 b) {
    return a.x * b.x + a.y * b.y + a.z * b.z + a.w * b.w;
}

__device__ __forceinline__ float dot8h(float4 a, float4 b, float acc) {
#if defined(__has_builtin) && __has_builtin(__builtin_amdgcn_fdot2)
    acc = __builtin_amdgcn_fdot2(__builtin_bit_cast(half2_t, a.x),
                                 __builtin_bit_cast(half2_t, b.x), acc, false);
    acc = __builtin_amdgcn_fdot2(__builtin_bit_cast(half2_t, a.y),
                                 __builtin_bit_cast(half2_t, b.y), acc, false);
    acc = __builtin_amdgcn_fdot2(__builtin_bit_cast(half2_t, a.z),
                                 __builtin_bit_cast(half2_t, b.z), acc, false);
    acc = __builtin_amdgcn_fdot2(__builtin_bit_cast(half2_t, a.w),
                                 __builtin_bit_cast(half2_t, b.w), acc, false);
#else
    const half2_t* ah = (const half2_t*)&a;
    const half2_t* bh = (const half2_t*)&b;
    #pragma unroll
    for (int k = 0; k < 4; ++k) {
        acc += (float)ah[k][0] * (float)bh[k][0];
        acc += (float)ah[k][1] * (float)bh[k][1];
    }
#endif
    return acc;
}

// ---------------- pass 0: fp32 -> fp16 table conversion ----------------
__global__ __launch_bounds__(256) void p0_convert(
    const float* __restrict__ in, _Float16* __restrict__ out, int n8) {
    int i = blockIdx.x * 256 + threadIdx.x;
    const int stride = gridDim.x * 256;
    for (; i < n8; i += stride) {
        const float4 f0 = ((const float4*)in)[2 * i + 0];
        const float4 f1 = ((const float4*)in)[2 * i + 1];
        v8h o;
        o[0] = (_Float16)f0.x; o[1] = (_Float16)f0.y;
        o[2] = (_Float16)f0.z; o[3] = (_Float16)f0.w;
        o[4] = (_Float16)f1.x; o[5] = (_Float16)f1.y;
        o[6] = (_Float16)f1.z; o[7] = (_Float16)f1.w;
        *(v8h*)(out + 8 * (size_t)i) = o;
    }
}

// ---------------- pass 1 (fp16, NCHUNK=4): per-chunk partial dots ----------------
__global__ __launch_bounds__(P1_THREADS) void p1_half(
    const _Float16* __restrict__ tab,
    const int* __restrict__ trip,
    int T,
    float2* __restrict__ part /* [NCHUNK][T] */) {

    const int lane  = threadIdx.x & 63;
    const int wave  = threadIdx.x >> 6;
    const int sub   = lane & 7;
    const int g     = lane >> 3;
    const int c     = blockIdx.x & (NCHUNK - 1);
    const int slice = blockIdx.x >> 2;

    const int perWave = T / WAVES_PER_CHUNK;       // 32 (exact)
    const int t0 = (slice * WPB + wave) * perWave;

    const _Float16* __restrict__ tabc = tab + c * CHUNKH + sub * 8;
    float2* __restrict__ outp = part + (size_t)c * T;

    #pragma unroll 4
    for (int i = 0; i < perWave; i += 8) {
        const int t = t0 + i + g;
        const int i0 = trip[3 * t + 0];
        const int i1 = trip[3 * t + 1];
        const int i2 = trip[3 * t + 2];

        const _Float16* A = tabc + (size_t)i0 * D;
        const _Float16* P = tabc + (size_t)i1 * D;
        const _Float16* N = tabc + (size_t)i2 * D;

        const float4 a0 = *(const float4*)(A);
        const float4 a1 = *(const float4*)(A + 64);
        const float4 p0 = *(const float4*)(P);
        const float4 p1 = *(const float4*)(P + 64);
        const float4 n0 = *(const float4*)(N);
        const float4 n1 = *(const float4*)(N + 64);

        float ap = dot8h(a0, p0, 0.f) + dot8h(a1, p1, 0.f);
        float an = dot8h(a0, n0, 0.f) + dot8h(a1, n1, 0.f);

        ap += __shfl_xor(ap, 1);
        ap += __shfl_xor(ap, 2);
        ap += __shfl_xor(ap, 4);
        an += __shfl_xor(an, 1);
        an += __shfl_xor(an, 2);
        an += __shfl_xor(an, 4);

        if (sub == 0) outp[t] = make_float2(ap, an);
    }
}

// ---------------- pass 1 (fp32, proven R5, FNCHUNK=8) ----------------
__global__ __launch_bounds__(P1_THREADS) void p1_chunk_dots(
    const float* __restrict__ emb,
    const int* __restrict__ trip,
    int T,
    float2* __restrict__ part) {

    const int lane  = threadIdx.x & 63;
    const int wave  = threadIdx.x >> 6;
    const int sub   = lane & 7;
    const int g     = lane >> 3;
    const int c     = blockIdx.x & (FNCHUNK - 1);
    const int slice = blockIdx.x >> 3;

    const int perWave = T / F_WPC;
    const int t0 = (slice * WPB + wave) * perWave;

    const float* __restrict__ embc = emb + c * CHUNKF + sub * 4;
    float2* __restrict__ outp = part + (size_t)c * T;

    #pragma unroll 2
    for (int i = 0; i < perWave; i += 8) {
        const int t = t0 + i + g;
        const int i0 = trip[3 * t + 0];
        const int i1 = trip[3 * t + 1];
        const int i2 = trip[3 * t + 2];

        const float* A = embc + (size_t)i0 * D;
        const float* P = embc + (size_t)i1 * D;
        const float* N = embc + (size_t)i2 * D;

        const float4 a0 = *(const float4*)(A);
        const float4 a1 = *(const float4*)(A + 32);
        const float4 p0 = *(const float4*)(P);
        const float4 p1 = *(const float4*)(P + 32);
        const float4 n0 = *(const float4*)(N);
        const float4 n1 = *(const float4*)(N + 32);

        float ap = dot4(a0, p0) + dot4(a1, p1);
        float an = dot4(a0, n0) + dot4(a1, n1);

        ap += __shfl_xor(ap, 1);
        ap += __shfl_xor(ap, 2);
        ap += __shfl_xor(ap, 4);
        an += __shfl_xor(an, 1);
        an += __shfl_xor(an, 2);
        an += __shfl_xor(an, 4);

        if (sub == 0) outp[t] = make_float2(ap, an);
    }
}

// ---------------- fused pass 2+3: combine, clip, exp, reduce, finalize ----------------
constexpr int P2_BLOCKS  = 256;
constexpr int P2_THREADS = 512;   // 1 triplet/thread: 256*512 = 131072

__global__ __launch_bounds__(P2_THREADS) void p2_fused(
    const float2* __restrict__ part, int T,
    float* __restrict__ bpart /* [P2_BLOCKS*3] */,
    int* __restrict__ ticket,
    float* __restrict__ out) {

    const int t = blockIdx.x * P2_THREADS + threadIdx.x;

    float ap = 0.f, an = 0.f;
    if (t < T) {
        #pragma unroll
        for (int c = 0; c < NCHUNK; ++c) {
            const float2 v = part[(size_t)c * T + t];
            ap += v.x; an += v.y;
        }
    }
    ap = fminf(fmaxf(ap, -1.0f), 1.0f);
    an = fminf(fmaxf(an, -1.0f), 1.0f);

    float s_loss = (t < T) ? __expf((an - ap) * MARGIN_INV) : 0.f;
    float s_ap   = (t < T) ? (1.0f - ap) : 0.f;
    float s_an   = (t < T) ? (1.0f - an) : 0.f;

    #pragma unroll
    for (int off = 32; off; off >>= 1) {
        s_loss += __shfl_xor(s_loss, off);
        s_ap   += __shfl_xor(s_ap, off);
        s_an   += __shfl_xor(s_an, off);
    }
    __shared__ float red[P2_THREADS / 64][3];
    __shared__ bool  amLast;
    const int lane = threadIdx.x & 63, wave = threadIdx.x >> 6;
    if (lane == 0) { red[wave][0] = s_loss; red[wave][1] = s_ap; red[wave][2] = s_an; }
    __syncthreads();
    if (threadIdx.x == 0) {
        float a = 0.f, b = 0.f, cc = 0.f;
        #pragma unroll
        for (int w = 0; w < P2_THREADS / 64; ++w) {
            a += red[w][0]; b += red[w][1]; cc += red[w][2];
        }
        bpart[blockIdx.x * 3 + 0] = a;
        bpart[blockIdx.x * 3 + 1] = b;
        bpart[blockIdx.x * 3 + 2] = cc;
        __threadfence();                               // publish bpart device-wide
        const int prev = atomicAdd(ticket, 1);         // device-scope by default
        amLast = (prev == gridDim.x - 1);
    }
    __syncthreads();
    if (!amLast) return;

    // last block: reduce the fixed-order bpart array (bit-deterministic)
    __threadfence();                                   // acquire others' bpart
    const int tid = threadIdx.x;
    float a = 0.f, b = 0.f, c = 0.f;
    for (int i = tid; i < P2_BLOCKS; i += P2_THREADS) {
        a += bpart[3 * i + 0];
        b += bpart[3 * i + 1];
        c += bpart[3 * i + 2];
    }
    #pragma unroll
    for (int off = 32; off; off >>= 1) {
        a += __shfl_xor(a, off);
        b += __shfl_xor(b, off);
        c += __shfl_xor(c, off);
    }
    __shared__ float fin[P2_THREADS / 64][3];
    if (lane == 0) { fin[wave][0] = a; fin[wave][1] = b; fin[wave][2] = c; }
    __syncthreads();
    if (tid == 0) {
        float A = 0.f, B = 0.f, C = 0.f;
        #pragma unroll
        for (int w = 0; w < P2_THREADS / 64; ++w) {
            A += fin[w][0]; B += fin[w][1]; C += fin[w][2];
        }
        const float inv = 1.0f / (float)T;
        out[0] = A * inv;
        out[1] = B * inv;
        out[2] = C * inv;
    }
}

// ---------------- pass 2/3 (separate, for fallback paths) ----------------
template<int NC>
__global__ __launch_bounds__(256) void p2_combine(
    const float2* __restrict__ part, int T,
    float* __restrict__ bpart) {

    const int t = blockIdx.x * 256 + threadIdx.x;

    float ap = 0.f, an = 0.f;
    if (t < T) {
        #pragma unroll
        for (int c = 0; c < NC; ++c) {
            const float2 v = part[(size_t)c * T + t];
            ap += v.x; an += v.y;
        }
    }
    ap = fminf(fmaxf(ap, -1.0f), 1.0f);
    an = fminf(fmaxf(an, -1.0f), 1.0f);

    float s_loss = (t < T) ? __expf((an - ap) * MARGIN_INV) : 0.f;
    float s_ap   = (t < T) ? (1.0f - ap) : 0.f;
    float s_an   = (t < T) ? (1.0f - an) : 0.f;

    #pragma unroll
    for (int off = 32; off; off >>= 1) {
        s_loss += __shfl_xor(s_loss, off);
        s_ap   += __shfl_xor(s_ap, off);
        s_an   += __shfl_xor(s_an, off);
    }
    __shared__ float red[4][3];
    const int lane = threadIdx.x & 63, wave = threadIdx.x >> 6;
    if (lane == 0) { red[wave][0] = s_loss; red[wave][1] = s_ap; red[wave][2] = s_an; }
    __syncthreads();
    if (threadIdx.x == 0) {
        float a = 0.f, b = 0.f, cc = 0.f;
        #pragma unroll
        for (int w = 0; w < 4; ++w) { a += red[w][0]; b += red[w][1]; cc += red[w][2]; }
        bpart[blockIdx.x * 3 + 0] = a;
        bpart[blockIdx.x * 3 + 1] = b;
        bpart[blockIdx.x * 3 + 2] = cc;
    }
}

__global__ __launch_bounds__(256) void p3_final(
    const float* __restrict__ bpart, int nblocks, int T,
    float* __restrict__ out) {

    const int tid = threadIdx.x;
    float a = 0.f, b = 0.f, c = 0.f;
    for (int i = tid; i < nblocks; i += 256) {
        a += bpart[3 * i + 0];
        b += bpart[3 * i + 1];
        c += bpart[3 * i + 2];
    }
    #pragma unroll
    for (int off = 32; off; off >>= 1) {
        a += __shfl_xor(a, off);
        b += __shfl_xor(b, off);
        c += __shfl_xor(c, off);
    }
    __shared__ float red[4][3];
    const int lane = tid & 63, wave = tid >> 6;
    if (lane == 0) { red[wave][0] = a; red[wave][1] = b; red[wave][2] = c; }
    __syncthreads();
    if (tid == 0) {
        float A = 0.f, B = 0.f, C = 0.f;
        #pragma unroll
        for (int w = 0; w < 4; ++w) { A += red[w][0]; B += red[w][1]; C += red[w][2]; }
        const float inv = 1.0f / (float)T;
        out[0] = A * inv;
        out[1] = B * inv;
        out[2] = C * inv;
    }
}

// ---------------- fallback (proven R2 kernel) ----------------
constexpr int FB_BLOCKS  = 2048;
constexpr int FB_THREADS = 256;
constexpr int FB_WPB     = FB_THREADS / 64;
constexpr int FB_TOTALW  = FB_BLOCKS * FB_WPB;

__global__ __launch_bounds__(FB_THREADS) void fb_main(
    const float* __restrict__ emb, const int* __restrict__ trip, int T,
    float* __restrict__ partials) {

    const int lane  = threadIdx.x & 63;
    const int wave  = threadIdx.x >> 6;
    const int gwave = blockIdx.x * FB_WPB + wave;

    float s_loss = 0.f, s_ap = 0.f, s_an = 0.f;
    for (int t = gwave; t < T; t += FB_TOTALW) {
        const int i0 = trip[3 * t + 0];
        const int i1 = trip[3 * t + 1];
        const int i2 = trip[3 * t + 2];
        const float4* a4 = (const float4*)(emb + (size_t)i0 * D) + (lane << 1);
        const float4* p4 = (const float4*)(emb + (size_t)i1 * D) + (lane << 1);
        const float4* n4 = (const float4*)(emb + (size_t)i2 * D) + (lane << 1);
        const float4 a0 = a4[0], a1 = a4[1];
        const float4 p0 = p4[0], p1 = p4[1];
        const float4 n0 = n4[0], n1 = n4[1];
        float ap = dot4(a0, p0) + dot4(a1, p1);
        float an = dot4(a0, n0) + dot4(a1, n1);
        #pragma unroll
        for (int off = 32; off; off >>= 1) { ap += __shfl_xor(ap, off); an += __shfl_xor(an, off); }
        ap = fminf(fmaxf(ap, -1.0f), 1.0f);
        an = fminf(fmaxf(an, -1.0f), 1.0f);
        s_loss += __expf((an - ap) * MARGIN_INV);
        s_ap   += 1.0f - ap;
        s_an   += 1.0f - an;
    }
    __shared__ float red[FB_WPB][3];
    if (lane == 0) { red[wave][0] = s_loss; red[wave][1] = s_ap; red[wave][2] = s_an; }
    __syncthreads();
    if (threadIdx.x == 0) {
        float a = 0.f, b = 0.f, c = 0.f;
        #pragma unroll
        for (int w = 0; w < FB_WPB; ++w) { a += red[w][0]; b += red[w][1]; c += red[w][2]; }
        partials[blockIdx.x * 3 + 0] = a;
        partials[blockIdx.x * 3 + 1] = b;
        partials[blockIdx.x * 3 + 2] = c;
    }
}

extern "C" void kernel_launch(void* const* d_in, const int* in_sizes, int n_in,
                              void* d_out, int out_size, void* d_ws, size_t ws_size,
                              hipStream_t stream) {
    const float* emb  = (const float*)d_in[0];
    const int*   trip = (const int*)d_in[1];
    float* out = (float*)d_out;
    const int T    = in_sizes[1] / 3;     // 131072
    const int nEmb = in_sizes[0];         // 8192*512

    const size_t tabBytes   = (size_t)nEmb * sizeof(_Float16);           // 8 MB
    const size_t partBytesH = (size_t)NCHUNK * T * sizeof(float2);       // 4 MB
    const size_t partBytesF = (size_t)FNCHUNK * T * sizeof(float2);      // 8 MB
    const size_t bpBytes    = 4096;                                      // bpart area
    const size_t tkBytes    = 256;                                       // ticket area

    const bool shapeH = (T % WAVES_PER_CHUNK) == 0 && (nEmb % 8) == 0 &&
                        (T == P2_BLOCKS * P2_THREADS);
    const bool shapeF = (T % F_WPC) == 0;

    if (shapeH && ws_size >= tabBytes + partBytesH + bpBytes + tkBytes) {
        _Float16* tab    = (_Float16*)d_ws;
        float2*   part   = (float2*)((char*)d_ws + tabBytes);
        float*    bpart  = (float*)((char*)d_ws + tabBytes + partBytesH);
        int*      ticket = (int*)((char*)d_ws + tabBytes + partBytesH + bpBytes);
        hipMemsetAsync(ticket, 0, sizeof(int), stream);
        p0_convert<<<2048, 256, 0, stream>>>(emb, tab, nEmb / 8);
        p1_half<<<P1_BLOCKS, P1_THREADS, 0, stream>>>(tab, trip, T, part);
        p2_fused<<<P2_BLOCKS, P2_THREADS, 0, stream>>>(part, T, bpart, ticket, out);
    } else if (shapeF && ws_size >= partBytesF + bpBytes) {
        float2* part  = (float2*)d_ws;
        float*  bpart = (float*)((char*)d_ws + partBytesF);
        p1_chunk_dots<<<P1_BLOCKS, P1_THREADS, 0, stream>>>(emb, trip, T, part);
        p2_combine<FNCHUNK><<<(T + 255) / 256, 256, 0, stream>>>(part, T, bpart);
        p3_final<<<1, 256, 0, stream>>>(bpart, (T + 255) / 256, T, out);
    } else {
        float* partials = (float*)d_ws;
        fb_main<<<FB_BLOCKS, FB_THREADS, 0, stream>>>(emb, trip, T, partials);
        p3_final<<<1, 256, 0, stream>>>(partials, FB_BLOCKS, T, out);
    }
}

// Round 10
// 44.588 us; speedup vs baseline: 1.1078x; 1.1078x over previous
//
#include <hip/hip_runtime.h>
#include <cstdint>

// OnlineTripletLoss: emb (8192,512) f32, triplets (131072,3) int32.
// Proven: D-sharding (chunk=blockIdx%NCHUNK -> XCD) keeps sub-tables
// L2-resident (FETCH 310MB->14MB); fp16 table halves gather sectors;
// gather is throughput-walled at ~2 cy/64B-sector/CU (R4/R5/R8 invariant).
// R10: fused p2+p3 last-block reduce, ticket reset done INSIDE p0 (R9's
// hipMemsetAsync-in-graph cost ~11us -> removed). 3 dispatches total.

#define MARGIN_INV (1.0f / 0.7f)
#define D 512
#define NCHUNK 4               // fp16 path: 4 chunks of 128 halfs (256 B)
#define CHUNKH 128

typedef _Float16 half2_t __attribute__((ext_vector_type(2)));
typedef _Float16 v8h     __attribute__((ext_vector_type(8)));

constexpr int P1_BLOCKS  = 4096;
constexpr int P1_THREADS = 256;        // 4 waves
constexpr int WPB        = P1_THREADS / 64;
constexpr int WAVES_PER_CHUNK = (P1_BLOCKS / NCHUNK) * WPB;   // 4096

// fp32 fallback path constants (proven R5 structure)
#define FNCHUNK 8
#define CHUNKF 64
constexpr int F_WPC = (P1_BLOCKS / FNCHUNK) * WPB;            // 2048

__device__ __forceinline__ float dot4(float4 a, float4 b) {
    return a.x * b.x + a.y * b.y + a.z * b.z + a.w * b.w;
}

__device__ __forceinline__ float dot8h(float4 a, float4 b, float acc) {
#if defined(__has_builtin) && __has_builtin(__builtin_amdgcn_fdot2)
    acc = __builtin_amdgcn_fdot2(__builtin_bit_cast(half2_t, a.x),
                                 __builtin_bit_cast(half2_t, b.x), acc, false);
    acc = __builtin_amdgcn_fdot2(__builtin_bit_cast(half2_t, a.y),
                                 __builtin_bit_cast(half2_t, b.y), acc, false);
    acc = __builtin_amdgcn_fdot2(__builtin_bit_cast(half2_t, a.z),
                                 __builtin_bit_cast(half2_t, b.z), acc, false);
    acc = __builtin_amdgcn_fdot2(__builtin_bit_cast(half2_t, a.w),
                                 __builtin_bit_cast(half2_t, b.w), acc, false);
#else
    const half2_t* ah = (const half2_t*)&a;
    const half2_t* bh = (const half2_t*)&b;
    #pragma unroll
    for (int k = 0; k < 4; ++k) {
        acc += (float)ah[k][0] * (float)bh[k][0];
        acc += (float)ah[k][1] * (float)bh[k][1];
    }
#endif
    return acc;
}

// ---------------- pass 0: fp32 -> fp16 table conversion (+ ticket reset) ----------------
__global__ __launch_bounds__(256) void p0_convert(
    const float* __restrict__ in, _Float16* __restrict__ out, int n8,
    int* __restrict__ ticket) {
    if (blockIdx.x == 0 && threadIdx.x == 0) *ticket = 0;   // reset for p2_fused
    int i = blockIdx.x * 256 + threadIdx.x;
    const int stride = gridDim.x * 256;
    for (; i < n8; i += stride) {
        const float4 f0 = ((const float4*)in)[2 * i + 0];
        const float4 f1 = ((const float4*)in)[2 * i + 1];
        v8h o;
        o[0] = (_Float16)f0.x; o[1] = (_Float16)f0.y;
        o[2] = (_Float16)f0.z; o[3] = (_Float16)f0.w;
        o[4] = (_Float16)f1.x; o[5] = (_Float16)f1.y;
        o[6] = (_Float16)f1.z; o[7] = (_Float16)f1.w;
        *(v8h*)(out + 8 * (size_t)i) = o;
    }
}

// ---------------- pass 1 (fp16, NCHUNK=4): per-chunk partial dots ----------------
__global__ __launch_bounds__(P1_THREADS) void p1_half(
    const _Float16* __restrict__ tab,
    const int* __restrict__ trip,
    int T,
    float2* __restrict__ part /* [NCHUNK][T] */) {

    const int lane  = threadIdx.x & 63;
    const int wave  = threadIdx.x >> 6;
    const int sub   = lane & 7;
    const int g     = lane >> 3;
    const int c     = blockIdx.x & (NCHUNK - 1);
    const int slice = blockIdx.x >> 2;

    const int perWave = T / WAVES_PER_CHUNK;       // 32 (exact)
    const int t0 = (slice * WPB + wave) * perWave;

    const _Float16* __restrict__ tabc = tab + c * CHUNKH + sub * 8;
    float2* __restrict__ outp = part + (size_t)c * T;

    #pragma unroll 4
    for (int i = 0; i < perWave; i += 8) {
        const int t = t0 + i + g;
        const int i0 = trip[3 * t + 0];
        const int i1 = trip[3 * t + 1];
        const int i2 = trip[3 * t + 2];

        const _Float16* A = tabc + (size_t)i0 * D;
        const _Float16* P = tabc + (size_t)i1 * D;
        const _Float16* N = tabc + (size_t)i2 * D;

        const float4 a0 = *(const float4*)(A);
        const float4 a1 = *(const float4*)(A + 64);
        const float4 p0 = *(const float4*)(P);
        const float4 p1 = *(const float4*)(P + 64);
        const float4 n0 = *(const float4*)(N);
        const float4 n1 = *(const float4*)(N + 64);

        float ap = dot8h(a0, p0, 0.f) + dot8h(a1, p1, 0.f);
        float an = dot8h(a0, n0, 0.f) + dot8h(a1, n1, 0.f);

        ap += __shfl_xor(ap, 1);
        ap += __shfl_xor(ap, 2);
        ap += __shfl_xor(ap, 4);
        an += __shfl_xor(an, 1);
        an += __shfl_xor(an, 2);
        an += __shfl_xor(an, 4);

        if (sub == 0) outp[t] = make_float2(ap, an);
    }
}

// ---------------- pass 1 (fp32, proven R5, FNCHUNK=8) ----------------
__global__ __launch_bounds__(P1_THREADS) void p1_chunk_dots(
    const float* __restrict__ emb,
    const int* __restrict__ trip,
    int T,
    float2* __restrict__ part) {

    const int lane  = threadIdx.x & 63;
    const int wave  = threadIdx.x >> 6;
    const int sub   = lane & 7;
    const int g     = lane >> 3;
    const int c     = blockIdx.x & (FNCHUNK - 1);
    const int slice = blockIdx.x >> 3;

    const int perWave = T / F_WPC;
    const int t0 = (slice * WPB + wave) * perWave;

    const float* __restrict__ embc = emb + c * CHUNKF + sub * 4;
    float2* __restrict__ outp = part + (size_t)c * T;

    #pragma unroll 2
    for (int i = 0; i < perWave; i += 8) {
        const int t = t0 + i + g;
        const int i0 = trip[3 * t + 0];
        const int i1 = trip[3 * t + 1];
        const int i2 = trip[3 * t + 2];

        const float* A = embc + (size_t)i0 * D;
        const float* P = embc + (size_t)i1 * D;
        const float* N = embc + (size_t)i2 * D;

        const float4 a0 = *(const float4*)(A);
        const float4 a1 = *(const float4*)(A + 32);
        const float4 p0 = *(const float4*)(P);
        const float4 p1 = *(const float4*)(P + 32);
        const float4 n0 = *(const float4*)(N);
        const float4 n1 = *(const float4*)(N + 32);

        float ap = dot4(a0, p0) + dot4(a1, p1);
        float an = dot4(a0, n0) + dot4(a1, n1);

        ap += __shfl_xor(ap, 1);
        ap += __shfl_xor(ap, 2);
        ap += __shfl_xor(ap, 4);
        an += __shfl_xor(an, 1);
        an += __shfl_xor(an, 2);
        an += __shfl_xor(an, 4);

        if (sub == 0) outp[t] = make_float2(ap, an);
    }
}

// ---------------- fused pass 2+3: combine, clip, exp, reduce, finalize ----------------
constexpr int P2_BLOCKS  = 256;
constexpr int P2_THREADS = 512;   // 1 triplet/thread: 256*512 = 131072

__global__ __launch_bounds__(P2_THREADS) void p2_fused(
    const float2* __restrict__ part, int T,
    float* __restrict__ bpart /* [P2_BLOCKS*3] */,
    int* __restrict__ ticket,
    float* __restrict__ out) {

    const int t = blockIdx.x * P2_THREADS + threadIdx.x;

    float ap = 0.f, an = 0.f;
    if (t < T) {
        #pragma unroll
        for (int c = 0; c < NCHUNK; ++c) {
            const float2 v = part[(size_t)c * T + t];
            ap += v.x; an += v.y;
        }
    }
    ap = fminf(fmaxf(ap, -1.0f), 1.0f);
    an = fminf(fmaxf(an, -1.0f), 1.0f);

    float s_loss = (t < T) ? __expf((an - ap) * MARGIN_INV) : 0.f;
    float s_ap   = (t < T) ? (1.0f - ap) : 0.f;
    float s_an   = (t < T) ? (1.0f - an) : 0.f;

    #pragma unroll
    for (int off = 32; off; off >>= 1) {
        s_loss += __shfl_xor(s_loss, off);
        s_ap   += __shfl_xor(s_ap, off);
        s_an   += __shfl_xor(s_an, off);
    }
    __shared__ float red[P2_THREADS / 64][3];
    __shared__ bool  amLast;
    const int lane = threadIdx.x & 63, wave = threadIdx.x >> 6;
    if (lane == 0) { red[wave][0] = s_loss; red[wave][1] = s_ap; red[wave][2] = s_an; }
    __syncthreads();
    if (threadIdx.x == 0) {
        float a = 0.f, b = 0.f, cc = 0.f;
        #pragma unroll
        for (int w = 0; w < P2_THREADS / 64; ++w) {
            a += red[w][0]; b += red[w][1]; cc += red[w][2];
        }
        bpart[blockIdx.x * 3 + 0] = a;
        bpart[blockIdx.x * 3 + 1] = b;
        bpart[blockIdx.x * 3 + 2] = cc;
        __threadfence();                               // publish bpart device-wide
        const int prev = atomicAdd(ticket, 1);         // device-scope by default
        amLast = (prev == gridDim.x - 1);
    }
    __syncthreads();
    if (!amLast) return;

    // last block: reduce the fixed-order bpart array (bit-deterministic)
    __threadfence();                                   // acquire others' bpart
    const int tid = threadIdx.x;
    float a = 0.f, b = 0.f, c = 0.f;
    for (int i = tid; i < P2_BLOCKS; i += P2_THREADS) {
        a += bpart[3 * i + 0];
        b += bpart[3 * i + 1];
        c += bpart[3 * i + 2];
    }
    #pragma unroll
    for (int off = 32; off; off >>= 1) {
        a += __shfl_xor(a, off);
        b += __shfl_xor(b, off);
        c += __shfl_xor(c, off);
    }
    __shared__ float fin[P2_THREADS / 64][3];
    if (lane == 0) { fin[wave][0] = a; fin[wave][1] = b; fin[wave][2] = c; }
    __syncthreads();
    if (tid == 0) {
        float A = 0.f, B = 0.f, C = 0.f;
        #pragma unroll
        for (int w = 0; w < P2_THREADS / 64; ++w) {
            A += fin[w][0]; B += fin[w][1]; C += fin[w][2];
        }
        const float inv = 1.0f / (float)T;
        out[0] = A * inv;
        out[1] = B * inv;
        out[2] = C * inv;
    }
}

// ---------------- pass 2/3 (separate, for fallback paths) ----------------
template<int NC>
__global__ __launch_bounds__(256) void p2_combine(
    const float2* __restrict__ part, int T,
    float* __restrict__ bpart) {

    const int t = blockIdx.x * 256 + threadIdx.x;

    float ap = 0.f, an = 0.f;
    if (t < T) {
        #pragma unroll
        for (int c = 0; c < NC; ++c) {
            const float2 v = part[(size_t)c * T + t];
            ap += v.x; an += v.y;
        }
    }
    ap = fminf(fmaxf(ap, -1.0f), 1.0f);
    an = fminf(fmaxf(an, -1.0f), 1.0f);

    float s_loss = (t < T) ? __expf((an - ap) * MARGIN_INV) : 0.f;
    float s_ap   = (t < T) ? (1.0f - ap) : 0.f;
    float s_an   = (t < T) ? (1.0f - an) : 0.f;

    #pragma unroll
    for (int off = 32; off; off >>= 1) {
        s_loss += __shfl_xor(s_loss, off);
        s_ap   += __shfl_xor(s_ap, off);
        s_an   += __shfl_xor(s_an, off);
    }
    __shared__ float red[4][3];
    const int lane = threadIdx.x & 63, wave = threadIdx.x >> 6;
    if (lane == 0) { red[wave][0] = s_loss; red[wave][1] = s_ap; red[wave][2] = s_an; }
    __syncthreads();
    if (threadIdx.x == 0) {
        float a = 0.f, b = 0.f, cc = 0.f;
        #pragma unroll
        for (int w = 0; w < 4; ++w) { a += red[w][0]; b += red[w][1]; cc += red[w][2]; }
        bpart[blockIdx.x * 3 + 0] = a;
        bpart[blockIdx.x * 3 + 1] = b;
        bpart[blockIdx.x * 3 + 2] = cc;
    }
}

__global__ __launch_bounds__(256) void p3_final(
    const float* __restrict__ bpart, int nblocks, int T,
    float* __restrict__ out) {

    const int tid = threadIdx.x;
    float a = 0.f, b = 0.f, c = 0.f;
    for (int i = tid; i < nblocks; i += 256) {
        a += bpart[3 * i + 0];
        b += bpart[3 * i + 1];
        c += bpart[3 * i + 2];
    }
    #pragma unroll
    for (int off = 32; off; off >>= 1) {
        a += __shfl_xor(a, off);
        b += __shfl_xor(b, off);
        c += __shfl_xor(c, off);
    }
    __shared__ float red[4][3];
    const int lane = tid & 63, wave = tid >> 6;
    if (lane == 0) { red[wave][0] = a; red[wave][1] = b; red[wave][2] = c; }
    __syncthreads();
    if (tid == 0) {
        float A = 0.f, B = 0.f, C = 0.f;
        #pragma unroll
        for (int w = 0; w < 4; ++w) { A += red[w][0]; B += red[w][1]; C += red[w][2]; }
        const float inv = 1.0f / (float)T;
        out[0] = A * inv;
        out[1] = B * inv;
        out[2] = C * inv;
    }
}

// ---------------- fallback (proven R2 kernel) ----------------
constexpr int FB_BLOCKS  = 2048;
constexpr int FB_THREADS = 256;
constexpr int FB_WPB     = FB_THREADS / 64;
constexpr int FB_TOTALW  = FB_BLOCKS * FB_WPB;

__global__ __launch_bounds__(FB_THREADS) void fb_main(
    const float* __restrict__ emb, const int* __restrict__ trip, int T,
    float* __restrict__ partials) {

    const int lane  = threadIdx.x & 63;
    const int wave  = threadIdx.x >> 6;
    const int gwave = blockIdx.x * FB_WPB + wave;

    float s_loss = 0.f, s_ap = 0.f, s_an = 0.f;
    for (int t = gwave; t < T; t += FB_TOTALW) {
        const int i0 = trip[3 * t + 0];
        const int i1 = trip[3 * t + 1];
        const int i2 = trip[3 * t + 2];
        const float4* a4 = (const float4*)(emb + (size_t)i0 * D) + (lane << 1);
        const float4* p4 = (const float4*)(emb + (size_t)i1 * D) + (lane << 1);
        const float4* n4 = (const float4*)(emb + (size_t)i2 * D) + (lane << 1);
        const float4 a0 = a4[0], a1 = a4[1];
        const float4 p0 = p4[0], p1 = p4[1];
        const float4 n0 = n4[0], n1 = n4[1];
        float ap = dot4(a0, p0) + dot4(a1, p1);
        float an = dot4(a0, n0) + dot4(a1, n1);
        #pragma unroll
        for (int off = 32; off; off >>= 1) { ap += __shfl_xor(ap, off); an += __shfl_xor(an, off); }
        ap = fminf(fmaxf(ap, -1.0f), 1.0f);
        an = fminf(fmaxf(an, -1.0f), 1.0f);
        s_loss += __expf((an - ap) * MARGIN_INV);
        s_ap   += 1.0f - ap;
        s_an   += 1.0f - an;
    }
    __shared__ float red[FB_WPB][3];
    if (lane == 0) { red[wave][0] = s_loss; red[wave][1] = s_ap; red[wave][2] = s_an; }
    __syncthreads();
    if (threadIdx.x == 0) {
        float a = 0.f, b = 0.f, c = 0.f;
        #pragma unroll
        for (int w = 0; w < FB_WPB; ++w) { a += red[w][0]; b += red[w][1]; c += red[w][2]; }
        partials[blockIdx.x * 3 + 0] = a;
        partials[blockIdx.x * 3 + 1] = b;
        partials[blockIdx.x * 3 + 2] = c;
    }
}

extern "C" void kernel_launch(void* const* d_in, const int* in_sizes, int n_in,
                              void* d_out, int out_size, void* d_ws, size_t ws_size,
                              hipStream_t stream) {
    const float* emb  = (const float*)d_in[0];
    const int*   trip = (const int*)d_in[1];
    float* out = (float*)d_out;
    const int T    = in_sizes[1] / 3;     // 131072
    const int nEmb = in_sizes[0];         // 8192*512

    const size_t tabBytes   = (size_t)nEmb * sizeof(_Float16);           // 8 MB
    const size_t partBytesH = (size_t)NCHUNK * T * sizeof(float2);       // 4 MB
    const size_t partBytesF = (size_t)FNCHUNK * T * sizeof(float2);      // 8 MB
    const size_t bpBytes    = 4096;                                      // bpart area
    const size_t tkBytes    = 256;                                       // ticket area

    const bool shapeH = (T % WAVES_PER_CHUNK) == 0 && (nEmb % 8) == 0 &&
                        (T == P2_BLOCKS * P2_THREADS);
    const bool shapeF = (T % F_WPC) == 0;

    if (shapeH && ws_size >= tabBytes + partBytesH + bpBytes + tkBytes) {
        _Float16* tab    = (_Float16*)d_ws;
        float2*   part   = (float2*)((char*)d_ws + tabBytes);
        float*    bpart  = (float*)((char*)d_ws + tabBytes + partBytesH);
        int*      ticket = (int*)((char*)d_ws + tabBytes + partBytesH + bpBytes);
        p0_convert<<<2048, 256, 0, stream>>>(emb, tab, nEmb / 8, ticket);
        p1_half<<<P1_BLOCKS, P1_THREADS, 0, stream>>>(tab, trip, T, part);
        p2_fused<<<P2_BLOCKS, P2_THREADS, 0, stream>>>(part, T, bpart, ticket, out);
    } else if (shapeF && ws_size >= partBytesF + bpBytes) {
        float2* part  = (float2*)d_ws;
        float*  bpart = (float*)((char*)d_ws + partBytesF);
        p1_chunk_dots<<<P1_BLOCKS, P1_THREADS, 0, stream>>>(emb, trip, T, part);
        p2_combine<FNCHUNK><<<(T + 255) / 256, 256, 0, stream>>>(part, T, bpart);
        p3_final<<<1, 256, 0, stream>>>(bpart, (T + 255) / 256, T, out);
    } else {
        float* partials = (float*)d_ws;
        fb_main<<<FB_BLOCKS, FB_THREADS, 0, stream>>>(emb, trip, T, partials);
        p3_final<<<1, 256, 0, stream>>>(partials, FB_BLOCKS, T, out);
    }
}

// Round 11
// 38.240 us; speedup vs baseline: 1.2917x; 1.1660x over previous
//
#include <hip/hip_runtime.h>
#include <cstdint>

// OnlineTripletLoss: emb (8192,512) f32, triplets (131072,3) int32.
// Final structure (R8, proven 38.5us): p0 fp32->fp16 table convert,
// p1 D-sharded gather+dot (chunk=blockIdx%4 -> XCD, 2MB sub-table
// L2-resident; gather at the L2 tag-rate wall ~16 req/cy/XCD),
// p2 combine+clip+exp+block-reduce, p3 final reduce.
// R11 tweak: partials packed as fp16 pairs (part traffic halved).
// R9/R10 lesson: last-block fusion (threadfence + cross-XCD atomics)
// costs MORE than the extra tiny launch on 8-XCD CDNA4 -> keep 4 kernels.

#define MARGIN_INV (1.0f / 0.7f)
#define D 512
#define NCHUNK 4               // fp16 path: 4 chunks of 128 halfs (256 B)
#define CHUNKH 128

typedef _Float16 half2_t __attribute__((ext_vector_type(2)));
typedef _Float16 v8h     __attribute__((ext_vector_type(8)));

constexpr int P1_BLOCKS  = 4096;
constexpr int P1_THREADS = 256;        // 4 waves
constexpr int WPB        = P1_THREADS / 64;
constexpr int WAVES_PER_CHUNK = (P1_BLOCKS / NCHUNK) * WPB;   // 4096

// fp32 fallback path constants (proven R5 structure)
#define FNCHUNK 8
#define CHUNKF 64
constexpr int F_WPC = (P1_BLOCKS / FNCHUNK) * WPB;            // 2048

__device__ __forceinline__ float dot4(float4 a, float4 b) {
    return a.x * b.x + a.y * b.y + a.z * b.z + a.w * b.w;
}

__device__ __forceinline__ float dot8h(float4 a, float4 b, float acc) {
#if defined(__has_builtin) && __has_builtin(__builtin_amdgcn_fdot2)
    acc = __builtin_amdgcn_fdot2(__builtin_bit_cast(half2_t, a.x),
                                 __builtin_bit_cast(half2_t, b.x), acc, false);
    acc = __builtin_amdgcn_fdot2(__builtin_bit_cast(half2_t, a.y),
                                 __builtin_bit_cast(half2_t, b.y), acc, false);
    acc = __builtin_amdgcn_fdot2(__builtin_bit_cast(half2_t, a.z),
                                 __builtin_bit_cast(half2_t, b.z), acc, false);
    acc = __builtin_amdgcn_fdot2(__builtin_bit_cast(half2_t, a.w),
                                 __builtin_bit_cast(half2_t, b.w), acc, false);
#else
    const half2_t* ah = (const half2_t*)&a;
    const half2_t* bh = (const half2_t*)&b;
    #pragma unroll
    for (int k = 0; k < 4; ++k) {
        acc += (float)ah[k][0] * (float)bh[k][0];
        acc += (float)ah[k][1] * (float)bh[k][1];
    }
#endif
    return acc;
}

__device__ __forceinline__ uint32_t pack_h2(float x, float y) {
    half2_t h; h[0] = (_Float16)x; h[1] = (_Float16)y;
    return __builtin_bit_cast(uint32_t, h);
}

// ---------------- pass 0: fp32 -> fp16 table conversion ----------------
__global__ __launch_bounds__(256) void p0_convert(
    const float* __restrict__ in, _Float16* __restrict__ out, int n8) {
    int i = blockIdx.x * 256 + threadIdx.x;
    const int stride = gridDim.x * 256;
    for (; i < n8; i += stride) {
        const float4 f0 = ((const float4*)in)[2 * i + 0];
        const float4 f1 = ((const float4*)in)[2 * i + 1];
        v8h o;
        o[0] = (_Float16)f0.x; o[1] = (_Float16)f0.y;
        o[2] = (_Float16)f0.z; o[3] = (_Float16)f0.w;
        o[4] = (_Float16)f1.x; o[5] = (_Float16)f1.y;
        o[6] = (_Float16)f1.z; o[7] = (_Float16)f1.w;
        *(v8h*)(out + 8 * (size_t)i) = o;
    }
}

// ---------------- pass 1 (fp16, NCHUNK=4): per-chunk partial dots ----------------
__global__ __launch_bounds__(P1_THREADS) void p1_half(
    const _Float16* __restrict__ tab,
    const int* __restrict__ trip,
    int T,
    uint32_t* __restrict__ part /* [NCHUNK][T] packed half2 */) {

    const int lane  = threadIdx.x & 63;
    const int wave  = threadIdx.x >> 6;
    const int sub   = lane & 7;
    const int g     = lane >> 3;
    const int c     = blockIdx.x & (NCHUNK - 1);
    const int slice = blockIdx.x >> 2;

    const int perWave = T / WAVES_PER_CHUNK;       // 32 (exact)
    const int t0 = (slice * WPB + wave) * perWave;

    const _Float16* __restrict__ tabc = tab + c * CHUNKH + sub * 8;
    uint32_t* __restrict__ outp = part + (size_t)c * T;

    #pragma unroll 4
    for (int i = 0; i < perWave; i += 8) {
        const int t = t0 + i + g;
        const int i0 = trip[3 * t + 0];
        const int i1 = trip[3 * t + 1];
        const int i2 = trip[3 * t + 2];

        const _Float16* A = tabc + (size_t)i0 * D;
        const _Float16* P = tabc + (size_t)i1 * D;
        const _Float16* N = tabc + (size_t)i2 * D;

        const float4 a0 = *(const float4*)(A);
        const float4 a1 = *(const float4*)(A + 64);
        const float4 p0 = *(const float4*)(P);
        const float4 p1 = *(const float4*)(P + 64);
        const float4 n0 = *(const float4*)(N);
        const float4 n1 = *(const float4*)(N + 64);

        float ap = dot8h(a0, p0, 0.f) + dot8h(a1, p1, 0.f);
        float an = dot8h(a0, n0, 0.f) + dot8h(a1, n1, 0.f);

        ap += __shfl_xor(ap, 1);
        ap += __shfl_xor(ap, 2);
        ap += __shfl_xor(ap, 4);
        an += __shfl_xor(an, 1);
        an += __shfl_xor(an, 2);
        an += __shfl_xor(an, 4);

        if (sub == 0) outp[t] = pack_h2(ap, an);
    }
}

// ---------------- pass 1 (fp32, proven R5, FNCHUNK=8) ----------------
__global__ __launch_bounds__(P1_THREADS) void p1_chunk_dots(
    const float* __restrict__ emb,
    const int* __restrict__ trip,
    int T,
    float2* __restrict__ part) {

    const int lane  = threadIdx.x & 63;
    const int wave  = threadIdx.x >> 6;
    const int sub   = lane & 7;
    const int g     = lane >> 3;
    const int c     = blockIdx.x & (FNCHUNK - 1);
    const int slice = blockIdx.x >> 3;

    const int perWave = T / F_WPC;
    const int t0 = (slice * WPB + wave) * perWave;

    const float* __restrict__ embc = emb + c * CHUNKF + sub * 4;
    float2* __restrict__ outp = part + (size_t)c * T;

    #pragma unroll 2
    for (int i = 0; i < perWave; i += 8) {
        const int t = t0 + i + g;
        const int i0 = trip[3 * t + 0];
        const int i1 = trip[3 * t + 1];
        const int i2 = trip[3 * t + 2];

        const float* A = embc + (size_t)i0 * D;
        const float* P = embc + (size_t)i1 * D;
        const float* N = embc + (size_t)i2 * D;

        const float4 a0 = *(const float4*)(A);
        const float4 a1 = *(const float4*)(A + 32);
        const float4 p0 = *(const float4*)(P);
        const float4 p1 = *(const float4*)(P + 32);
        const float4 n0 = *(const float4*)(N);
        const float4 n1 = *(const float4*)(N + 32);

        float ap = dot4(a0, p0) + dot4(a1, p1);
        float an = dot4(a0, n0) + dot4(a1, n1);

        ap += __shfl_xor(ap, 1);
        ap += __shfl_xor(ap, 2);
        ap += __shfl_xor(ap, 4);
        an += __shfl_xor(an, 1);
        an += __shfl_xor(an, 2);
        an += __shfl_xor(an, 4);

        if (sub == 0) outp[t] = make_float2(ap, an);
    }
}

// ---------------- pass 2 (fp16 path): combine, clip, exp, block-reduce ----------------
constexpr int P2_BLOCKS  = 512;
constexpr int P2_THREADS = 256;

__global__ __launch_bounds__(P2_THREADS) void p2_combine_h(
    const uint32_t* __restrict__ part, int T,
    float* __restrict__ bpart /* [P2_BLOCKS*3] */) {

    const int t = blockIdx.x * P2_THREADS + threadIdx.x;

    float ap = 0.f, an = 0.f;
    if (t < T) {
        #pragma unroll
        for (int c = 0; c < NCHUNK; ++c) {
            const half2_t v = __builtin_bit_cast(half2_t, part[(size_t)c * T + t]);
            ap += (float)v[0]; an += (float)v[1];
        }
    }
    ap = fminf(fmaxf(ap, -1.0f), 1.0f);
    an = fminf(fmaxf(an, -1.0f), 1.0f);

    float s_loss = (t < T) ? __expf((an - ap) * MARGIN_INV) : 0.f;
    float s_ap   = (t < T) ? (1.0f - ap) : 0.f;
    float s_an   = (t < T) ? (1.0f - an) : 0.f;

    #pragma unroll
    for (int off = 32; off; off >>= 1) {
        s_loss += __shfl_xor(s_loss, off);
        s_ap   += __shfl_xor(s_ap, off);
        s_an   += __shfl_xor(s_an, off);
    }
    __shared__ float red[4][3];
    const int lane = threadIdx.x & 63, wave = threadIdx.x >> 6;
    if (lane == 0) { red[wave][0] = s_loss; red[wave][1] = s_ap; red[wave][2] = s_an; }
    __syncthreads();
    if (threadIdx.x == 0) {
        float a = 0.f, b = 0.f, cc = 0.f;
        #pragma unroll
        for (int w = 0; w < 4; ++w) { a += red[w][0]; b += red[w][1]; cc += red[w][2]; }
        bpart[blockIdx.x * 3 + 0] = a;
        bpart[blockIdx.x * 3 + 1] = b;
        bpart[blockIdx.x * 3 + 2] = cc;
    }
}

// ---------------- pass 2 (fp32 fallback path) ----------------
template<int NC>
__global__ __launch_bounds__(256) void p2_combine(
    const float2* __restrict__ part, int T,
    float* __restrict__ bpart) {

    const int t = blockIdx.x * 256 + threadIdx.x;

    float ap = 0.f, an = 0.f;
    if (t < T) {
        #pragma unroll
        for (int c = 0; c < NC; ++c) {
            const float2 v = part[(size_t)c * T + t];
            ap += v.x; an += v.y;
        }
    }
    ap = fminf(fmaxf(ap, -1.0f), 1.0f);
    an = fminf(fmaxf(an, -1.0f), 1.0f);

    float s_loss = (t < T) ? __expf((an - ap) * MARGIN_INV) : 0.f;
    float s_ap   = (t < T) ? (1.0f - ap) : 0.f;
    float s_an   = (t < T) ? (1.0f - an) : 0.f;

    #pragma unroll
    for (int off = 32; off; off >>= 1) {
        s_loss += __shfl_xor(s_loss, off);
        s_ap   += __shfl_xor(s_ap, off);
        s_an   += __shfl_xor(s_an, off);
    }
    __shared__ float red[4][3];
    const int lane = threadIdx.x & 63, wave = threadIdx.x >> 6;
    if (lane == 0) { red[wave][0] = s_loss; red[wave][1] = s_ap; red[wave][2] = s_an; }
    __syncthreads();
    if (threadIdx.x == 0) {
        float a = 0.f, b = 0.f, cc = 0.f;
        #pragma unroll
        for (int w = 0; w < 4; ++w) { a += red[w][0]; b += red[w][1]; cc += red[w][2]; }
        bpart[blockIdx.x * 3 + 0] = a;
        bpart[blockIdx.x * 3 + 1] = b;
        bpart[blockIdx.x * 3 + 2] = cc;
    }
}

// ---------------- pass 3: final reduce ----------------
__global__ __launch_bounds__(256) void p3_final(
    const float* __restrict__ bpart, int nblocks, int T,
    float* __restrict__ out) {

    const int tid = threadIdx.x;
    float a = 0.f, b = 0.f, c = 0.f;
    for (int i = tid; i < nblocks; i += 256) {
        a += bpart[3 * i + 0];
        b += bpart[3 * i + 1];
        c += bpart[3 * i + 2];
    }
    #pragma unroll
    for (int off = 32; off; off >>= 1) {
        a += __shfl_xor(a, off);
        b += __shfl_xor(b, off);
        c += __shfl_xor(c, off);
    }
    __shared__ float red[4][3];
    const int lane = tid & 63, wave = tid >> 6;
    if (lane == 0) { red[wave][0] = a; red[wave][1] = b; red[wave][2] = c; }
    __syncthreads();
    if (tid == 0) {
        float A = 0.f, B = 0.f, C = 0.f;
        #pragma unroll
        for (int w = 0; w < 4; ++w) { A += red[w][0]; B += red[w][1]; C += red[w][2]; }
        const float inv = 1.0f / (float)T;
        out[0] = A * inv;
        out[1] = B * inv;
        out[2] = C * inv;
    }
}

// ---------------- fallback (proven R2 kernel) ----------------
constexpr int FB_BLOCKS  = 2048;
constexpr int FB_THREADS = 256;
constexpr int FB_WPB     = FB_THREADS / 64;
constexpr int FB_TOTALW  = FB_BLOCKS * FB_WPB;

__global__ __launch_bounds__(FB_THREADS) void fb_main(
    const float* __restrict__ emb, const int* __restrict__ trip, int T,
    float* __restrict__ partials) {

    const int lane  = threadIdx.x & 63;
    const int wave  = threadIdx.x >> 6;
    const int gwave = blockIdx.x * FB_WPB + wave;

    float s_loss = 0.f, s_ap = 0.f, s_an = 0.f;
    for (int t = gwave; t < T; t += FB_TOTALW) {
        const int i0 = trip[3 * t + 0];
        const int i1 = trip[3 * t + 1];
        const int i2 = trip[3 * t + 2];
        const float4* a4 = (const float4*)(emb + (size_t)i0 * D) + (lane << 1);
        const float4* p4 = (const float4*)(emb + (size_t)i1 * D) + (lane << 1);
        const float4* n4 = (const float4*)(emb + (size_t)i2 * D) + (lane << 1);
        const float4 a0 = a4[0], a1 = a4[1];
        const float4 p0 = p4[0], p1 = p4[1];
        const float4 n0 = n4[0], n1 = n4[1];
        float ap = dot4(a0, p0) + dot4(a1, p1);
        float an = dot4(a0, n0) + dot4(a1, n1);
        #pragma unroll
        for (int off = 32; off; off >>= 1) { ap += __shfl_xor(ap, off); an += __shfl_xor(an, off); }
        ap = fminf(fmaxf(ap, -1.0f), 1.0f);
        an = fminf(fmaxf(an, -1.0f), 1.0f);
        s_loss += __expf((an - ap) * MARGIN_INV);
        s_ap   += 1.0f - ap;
        s_an   += 1.0f - an;
    }
    __shared__ float red[FB_WPB][3];
    if (lane == 0) { red[wave][0] = s_loss; red[wave][1] = s_ap; red[wave][2] = s_an; }
    __syncthreads();
    if (threadIdx.x == 0) {
        float a = 0.f, b = 0.f, c = 0.f;
        #pragma unroll
        for (int w = 0; w < FB_WPB; ++w) { a += red[w][0]; b += red[w][1]; c += red[w][2]; }
        partials[blockIdx.x * 3 + 0] = a;
        partials[blockIdx.x * 3 + 1] = b;
        partials[blockIdx.x * 3 + 2] = c;
    }
}

extern "C" void kernel_launch(void* const* d_in, const int* in_sizes, int n_in,
                              void* d_out, int out_size, void* d_ws, size_t ws_size,
                              hipStream_t stream) {
    const float* emb  = (const float*)d_in[0];
    const int*   trip = (const int*)d_in[1];
    float* out = (float*)d_out;
    const int T    = in_sizes[1] / 3;     // 131072
    const int nEmb = in_sizes[0];         // 8192*512

    const size_t tabBytes   = (size_t)nEmb * sizeof(_Float16);           // 8 MB
    const size_t partBytesH = (size_t)NCHUNK * T * sizeof(uint32_t);     // 2 MB
    const size_t partBytesF = (size_t)FNCHUNK * T * sizeof(float2);      // 8 MB
    const size_t bpBytes    = 8192;                                      // bpart area

    const bool shapeH = (T % WAVES_PER_CHUNK) == 0 && (nEmb % 8) == 0;
    const bool shapeF = (T % F_WPC) == 0;

    if (shapeH && ws_size >= tabBytes + partBytesH + bpBytes) {
        _Float16* tab   = (_Float16*)d_ws;
        uint32_t* part  = (uint32_t*)((char*)d_ws + tabBytes);
        float*    bpart = (float*)((char*)d_ws + tabBytes + partBytesH);
        p0_convert<<<2048, 256, 0, stream>>>(emb, tab, nEmb / 8);
        p1_half<<<P1_BLOCKS, P1_THREADS, 0, stream>>>(tab, trip, T, part);
        p2_combine_h<<<(T + P2_THREADS - 1) / P2_THREADS, P2_THREADS, 0, stream>>>(part, T, bpart);
        p3_final<<<1, 256, 0, stream>>>(bpart, (T + P2_THREADS - 1) / P2_THREADS, T, out);
    } else if (shapeF && ws_size >= partBytesF + bpBytes) {
        float2* part  = (float2*)d_ws;
        float*  bpart = (float*)((char*)d_ws + partBytesF);
        p1_chunk_dots<<<P1_BLOCKS, P1_THREADS, 0, stream>>>(emb, trip, T, part);
        p2_combine<FNCHUNK><<<(T + 255) / 256, 256, 0, stream>>>(part, T, bpart);
        p3_final<<<1, 256, 0, stream>>>(bpart, (T + 255) / 256, T, out);
    } else {
        float* partials = (float*)d_ws;
        fb_main<<<FB_BLOCKS, FB_THREADS, 0, stream>>>(emb, trip, T, partials);
        p3_final<<<1, 256, 0, stream>>>(partials, FB_BLOCKS, T, out);
    }
}